// Round 1
// baseline (1017.386 us; speedup 1.0000x reference)
//
#include <hip/hip_runtime.h>
#include <hip/hip_bf16.h>
#include <stdint.h>

typedef __bf16 bf16;
typedef __bf16 bf16x8 __attribute__((ext_vector_type(8)));
typedef __bf16 bf16x4v __attribute__((ext_vector_type(4)));
typedef float f32x4 __attribute__((ext_vector_type(4)));

#define AS1 __attribute__((address_space(1)))
#define AS3 __attribute__((address_space(3)))

__device__ __forceinline__ void g2lds16(const bf16* g, bf16* l) {
  // global -> LDS async copy, 16 bytes per lane. LDS dest must be
  // wave-uniform base + lane*16 (caller guarantees this mapping).
  __builtin_amdgcn_global_load_lds((AS1 void*)(uintptr_t)g, (AS3 void*)l, 16, 0, 0);
}

// ---------------- prep: fold s (and 1/sqrt(C) for layer 3) into W, cast bf16 ----------------
__global__ void prep_weights_k(const float* __restrict__ W, const float* __restrict__ s,
                               const float* __restrict__ b, bf16* __restrict__ Wb,
                               float* __restrict__ bb) {
  int idx = blockIdx.x * 256 + threadIdx.x;     // 7*512*512 threads
  int c = idx & 511;
  int o = (idx >> 9) & 511;
  int l = idx >> 18;
  const float r = 0.04419417382415922f;         // 1/sqrt(512), folded into f_object layer 2 (idx 3)
  float f = (l == 3) ? r : 1.0f;
  Wb[idx] = (bf16)(W[idx] * s[(l << 9) + o] * f);
  if (c == 0) bb[(l << 9) + o] = b[(l << 9) + o] * f;
}

// ---------------- transpose + cast: in [z][R][Cc] f32 -> out [z][Cc][R] bf16 ----------------
__global__ void transpose_cast_k(const float* __restrict__ in, bf16* __restrict__ out,
                                 int R, int Cc) {
  __shared__ float tile[32][33];
  int c0 = blockIdx.x * 32, r0 = blockIdx.y * 32;
  size_t zoff = (size_t)blockIdx.z * R * Cc;
  int tx = threadIdx.x, ty = threadIdx.y;       // block (32, 8)
#pragma unroll
  for (int i = 0; i < 32; i += 8)
    tile[ty + i][tx] = in[zoff + (size_t)(r0 + ty + i) * Cc + c0 + tx];
  __syncthreads();
#pragma unroll
  for (int i = 0; i < 32; i += 8)
    out[zoff + (size_t)(c0 + ty + i) * R + r0 + tx] = (bf16)tile[tx][ty + i];
}

// ---------------- row softmax: sim [rows][256] f32 -> P [rows][256] bf16, one wave per row ----
__global__ void softmax_k(const float* __restrict__ sim, bf16* __restrict__ P) {
  int row = blockIdx.x * 4 + (threadIdx.x >> 6);
  int lane = threadIdx.x & 63;
  const float4 v = ((const float4*)(sim + (size_t)row * 256))[lane];
  float m = fmaxf(fmaxf(v.x, v.y), fmaxf(v.z, v.w));
#pragma unroll
  for (int o = 32; o > 0; o >>= 1) m = fmaxf(m, __shfl_xor(m, o));
  float e0 = __expf(v.x - m), e1 = __expf(v.y - m);
  float e2 = __expf(v.z - m), e3 = __expf(v.w - m);
  float sum = e0 + e1 + e2 + e3;
#pragma unroll
  for (int o = 32; o > 0; o >>= 1) sum += __shfl_xor(sum, o);
  float inv = 1.0f / sum;
  bf16x4v pk;
  pk.x = (bf16)(e0 * inv); pk.y = (bf16)(e1 * inv);
  pk.z = (bf16)(e2 * inv); pk.w = (bf16)(e3 * inv);
  ((bf16x4v*)(P + (size_t)row * 256))[lane] = pk;
}

// ---------------- generic NT GEMM (m97 structure) ----------------
// A: [z][M][Kd] (K contiguous), B: [z][N][Kd] (K contiguous), OUT: [z][M][N] (N contiguous)
// OUT[m][n] = act( sum_k A[m][k]*B[n][k] + bias )
// BIASMODE: 0 none, 1 bias[n-col] (out-channel on N), 2 bias[m-row] (out-channel on M)
// Requires M%128==0, N%128==0, Kd%64==0 (true for all shapes here).
template <bool RELU, bool OUTF32, int BIASMODE>
__global__ __launch_bounds__(256, 2) void gemm_nt(
    const bf16* __restrict__ A, long sAb,
    const bf16* __restrict__ B, long sBb,
    void* __restrict__ OUT, long sOb,
    const float* __restrict__ bias,
    int M, int N, int Kd) {
  __shared__ bf16 sA[128][64];
  __shared__ bf16 sB[128][64];
  const int n0 = blockIdx.x * 128;
  const int m0 = blockIdx.y * 128;
  const bf16* Ab = A + (size_t)blockIdx.z * sAb;
  const bf16* Bb = B + (size_t)blockIdx.z * sBb;
  const int t = threadIdx.x;
  const int lane = t & 63;
  const int w = t >> 6;
  const int wm = (w & 1) << 6;       // wave's 64x64 quadrant
  const int wn = (w >> 1) << 6;
  const int srow = t >> 3;           // staging: 32 rows per issue, 8x16B chunks per row
  const int scol = (t & 7) << 3;

  f32x4 acc[4][4] = {};

  const int fr = lane & 15;          // MFMA A/B frag: m/n = lane&15, k = (lane>>4)*8 + j
  const int fq = (lane >> 4) << 3;

  for (int k0 = 0; k0 < Kd; k0 += 64) {
#pragma unroll
    for (int i = 0; i < 4; i++) {
      g2lds16(Ab + (size_t)(m0 + i * 32 + srow) * Kd + (k0 + scol), &sA[i * 32 + srow][scol]);
      g2lds16(Bb + (size_t)(n0 + i * 32 + srow) * Kd + (k0 + scol), &sB[i * 32 + srow][scol]);
    }
    __syncthreads();
#pragma unroll
    for (int kk = 0; kk < 64; kk += 32) {
      bf16x8 af[4], bfv[4];
#pragma unroll
      for (int i = 0; i < 4; i++) af[i] = *(const bf16x8*)&sA[wm + i * 16 + fr][kk + fq];
#pragma unroll
      for (int j = 0; j < 4; j++) bfv[j] = *(const bf16x8*)&sB[wn + j * 16 + fr][kk + fq];
#pragma unroll
      for (int i = 0; i < 4; i++)
#pragma unroll
        for (int j = 0; j < 4; j++)
          acc[i][j] = __builtin_amdgcn_mfma_f32_16x16x32_bf16(af[i], bfv[j], acc[i][j], 0, 0, 0);
    }
    __syncthreads();
  }

  // epilogue: D layout col = lane&15, row = (lane>>4)*4 + r  [m89/m91-verified]
  const int rb = m0 + wm + ((lane >> 4) << 2);
  const int cb = n0 + wn + (lane & 15);
#pragma unroll
  for (int i = 0; i < 4; i++) {
#pragma unroll
    for (int r = 0; r < 4; r++) {
      const int orow = rb + i * 16 + r;
#pragma unroll
      for (int j = 0; j < 4; j++) {
        const int oc = cb + j * 16;
        float vv = acc[i][j][r];
        if (BIASMODE == 1) vv += bias[oc];
        else if (BIASMODE == 2) vv += bias[orow];
        if (RELU) vv = fmaxf(vv, 0.0f);
        if (OUTF32)
          ((float*)OUT)[(size_t)blockIdx.z * sOb + (size_t)orow * N + oc] = vv;
        else
          ((bf16*)OUT)[(size_t)blockIdx.z * sOb + (size_t)orow * N + oc] = (bf16)vv;
      }
    }
  }
}

extern "C" void kernel_launch(void* const* d_in, const int* in_sizes, int n_in,
                              void* d_out, int out_size, void* d_ws, size_t ws_size,
                              hipStream_t stream) {
  const float* x = (const float*)d_in[0];      // [8, 512, 128, 128]
  const float* proxy = (const float*)d_in[1];  // [8, 512, 256]
  const float* W = (const float*)d_in[2];      // [7, 512, 512]
  const float* s = (const float*)d_in[3];      // [7, 512]
  const float* b = (const float*)d_in[4];      // [7, 512]
  float* out = (float*)d_out;                  // [8, 512, 16384] fp32

  const int C = 512, K = 256, NB = 8, HW = 16384;
  const size_t MiB = 1024 * 1024;
  char* ws = (char*)d_ws;
  if (ws_size < 272 * MiB) return;  // need 272 MiB of scratch

  bf16* Wb   = (bf16*)(ws + 0);            // 7*512*512 bf16 = 3.5 MiB
  float* bb  = (float*)(ws + 3670016);     // 7*512 f32
  bf16* pT   = (bf16*)(ws + 4 * MiB);      // [8][256][512]
  bf16* k1   = (bf16*)(ws + 6 * MiB);      // [8][256][512]
  bf16* key  = (bf16*)(ws + 8 * MiB);      // [8][256][512]  (1/sqrt(C) folded in)
  bf16* t2   = (bf16*)(ws + 10 * MiB);     // [8][256][512]
  bf16* v    = (bf16*)(ws + 12 * MiB);     // [8][512][256]  value^T: [c][k]
  bf16* bufA = (bf16*)(ws + 16 * MiB);     // 128 MiB: xb -> q -> P
  bf16* bufB = (bf16*)(ws + 144 * MiB);    // 128 MiB: t0 -> sim(f32) -> ctx

  bf16* xb  = bufA;            // [8][16384][512]
  bf16* t0  = bufB;            // [8][16384][512]
  bf16* q   = bufA;            // overwrites xb (dead after fp0)
  float* simf = (float*)bufB;  // [8][16384][256] f32, overwrites t0 (dead after fp1)
  bf16* P   = bufA;            // [8][16384][256], overwrites q (dead after sim)
  bf16* ctx = bufB;            // [8][16384][512], overwrites sim (dead after softmax)

  const long KC = (long)K * C;       // 131072
  const long HWC = (long)HW * C;     // 8388608
  const long HWK = (long)HW * K;     // 4194304

  // 1. fold scales into weights
  prep_weights_k<<<7 * 512 * 512 / 256, 256, 0, stream>>>(W, s, b, Wb, bb);
  // 2. transpose+cast proxy [n,C,K] -> pT [n,K,C]
  transpose_cast_k<<<dim3(K / 32, C / 32, NB), dim3(32, 8), 0, stream>>>(proxy, pT, C, K);
  // 3. transpose+cast x [n,C,HW] -> xb [n,HW,C]
  transpose_cast_k<<<dim3(HW / 32, C / 32, NB), dim3(32, 8), 0, stream>>>(x, xb, C, HW);
  // 4. fo0: k1 = relu(pT·W2^T + b2)
  gemm_nt<true, false, 1><<<dim3(C / 128, K / 128, NB), 256, 0, stream>>>(
      pT, KC, Wb + 2 * 262144, 0, k1, KC, bb + 2 * 512, K, C, C);
  // 5. fo1: key = relu(k1·W3'^T + b3')   (scaled by 1/sqrt(C))
  gemm_nt<true, false, 1><<<dim3(C / 128, K / 128, NB), 256, 0, stream>>>(
      k1, KC, Wb + 3 * 262144, 0, key, KC, bb + 3 * 512, K, C, C);
  // 6. fd0: t2 = relu(pT·W4^T + b4)
  gemm_nt<true, false, 1><<<dim3(C / 128, K / 128, NB), 256, 0, stream>>>(
      pT, KC, Wb + 4 * 262144, 0, t2, KC, bb + 4 * 512, K, C, C);
  // 7. fd1 (swapped): v[c][k] = relu(W5'·t2^T + b5)  -> value^T layout [C][K]
  gemm_nt<true, false, 2><<<dim3(K / 128, C / 128, NB), 256, 0, stream>>>(
      Wb + 5 * 262144, 0, t2, KC, v, (long)C * K, bb + 5 * 512, C, K, C);
  // 8. fp0: t0 = relu(xb·W0^T + b0)
  gemm_nt<true, false, 1><<<dim3(C / 128, HW / 128, NB), 256, 0, stream>>>(
      xb, HWC, Wb, 0, t0, HWC, bb, HW, C, C);
  // 9. fp1: q = relu(t0·W1^T + b1)
  gemm_nt<true, false, 1><<<dim3(C / 128, HW / 128, NB), 256, 0, stream>>>(
      t0, HWC, Wb + 1 * 262144, 0, q, HWC, bb + 512, HW, C, C);
  // 10. sim = q·key^T (already scaled), fp32 out
  gemm_nt<false, true, 0><<<dim3(K / 128, HW / 128, NB), 256, 0, stream>>>(
      q, HWC, key, KC, simf, HWK, nullptr, HW, K, C);
  // 11. softmax over the 256 regions, P bf16
  softmax_k<<<NB * HW / 4, 256, 0, stream>>>(simf, P);
  // 12. ctx = P·v^T  -> [n][hw][c]
  gemm_nt<false, false, 0><<<dim3(C / 128, HW / 128, NB), 256, 0, stream>>>(
      P, HWK, v, (long)C * K, ctx, HWC, nullptr, HW, C, K);
  // 13. fup (swapped): out[c][hw] = relu(W6'·ctx^T + b6), fp32 directly to d_out
  gemm_nt<true, true, 2><<<dim3(HW / 128, C / 128, NB), 256, 0, stream>>>(
      Wb + 6 * 262144, 0, ctx, HWC, out, HWC, bb + 6 * 512, C, HW, C);
}